// Round 10
// baseline (232.949 us; speedup 1.0000x reference)
//
#include <hip/hip_runtime.h>

#define N_TOK 8192
#define KDIM  4096
#define NE    16
#define TPB   16                   // tokens per block (4 per wave)
#define NH    2                    // K halves (split-K)
#define KH    (KDIM / NH)          // 2048
#define CHUNK 256                  // k per chunk
#define NCH   (KH / CHUNK)         // 8 chunks per half
#define GSTR  260                  // gateT row stride in floats (256 + 4 pad)
#define GBUF  (NE * GSTR)          // 4160 floats per LDS buffer

// R16: amortize the gate-LDS cost over 2x tokens per wave.
// R15 (coalesced row-streaming) = best total 192.76. Remaining on-model
// cost: per wave-chunk, gate side = 16 ds_read_b128 (~192cy) + 16 scalar
// transpose-writes (~96cy) vs only 256 FMAs, amortized over just 2 tokens.
// Per-CU gate LDS reads ~4MB ~= 13-20us of LDS pipe -- same order as the
// 21.3us HBM floor: a real co-limiter. Both costs scale 1/(tokens-per-wave).
// R16: wave owns 4 tokens (acc[4][16]); block does HALF of K (8 chunks) so
// grid stays 1024 = 4 blocks/CU = 16 waves/CU (measured TLP optimum).
// Gate LDS + staging instrs halve per token; x traffic unchanged and still
// fill-shaped (1KB contiguous per instruction). ws = 2 half-partials;
// finalize sums them + top2. VGPR ~120 pinned <=128 by launch_bounds(256,4).
// Prediction: logits 70->45-55 (total ~170-180) OR 33->26-29 (total
// ~187-190) -- outcome disambiguates the decomposition. Check VGPR<=128,
// no scratch, LDS conflicts ~0.
__global__ __launch_bounds__(256, 4)
void router_logits(const float* __restrict__ x, const float* __restrict__ gate,
                   float* __restrict__ ws) {
  __shared__ __align__(16) float glds[2 * GBUF];   // 33.3 KB
  const int tid  = threadIdx.x;
  const int lane = tid & 63;
  const int w    = __builtin_amdgcn_readfirstlane(tid >> 6);
  const int g    = blockIdx.x >> 1;                // token group (512)
  const int h    = blockIdx.x & 1;                 // K half
  const int t0   = g * TPB;
  const int tokb = t0 + w * 4;                     // wave's 4 tokens

  const float4* gsrc = (const float4*)gate + (size_t)h * (KH * NE / 4);

  // ---- prologue: stage gate chunk 0 into buf0, load regs for chunk 1 ----
  float4 gr[4];
#pragma unroll
  for (int u = 0; u < 4; ++u) gr[u] = gsrc[u * 256 + tid];
#pragma unroll
  for (int u = 0; u < 4; ++u) {                    // transpose: gateT[e][k]
    int f4 = u * 256 + tid, k = f4 >> 2, j = f4 & 3;
    glds[(4 * j + 0) * GSTR + k] = gr[u].x;
    glds[(4 * j + 1) * GSTR + k] = gr[u].y;
    glds[(4 * j + 2) * GSTR + k] = gr[u].z;
    glds[(4 * j + 3) * GSTR + k] = gr[u].w;
  }
#pragma unroll
  for (int u = 0; u < 4; ++u) gr[u] = gsrc[1024 + u * 256 + tid];

  const float4* xr[4];
#pragma unroll
  for (int t = 0; t < 4; ++t)
    xr[t] = (const float4*)(x + (size_t)(tokb + t) * KDIM) + h * (KH / 4);

  float4 xc[4], xn[4];
#pragma unroll
  for (int t = 0; t < 4; ++t) xc[t] = xr[t][lane]; // chunk 0: 1KB/instr/wave

  float acc[4][NE];
#pragma unroll
  for (int t = 0; t < 4; ++t)
#pragma unroll
    for (int e = 0; e < NE; ++e) acc[t][e] = 0.f;

  __syncthreads();                                 // buf0 visible

  const float4* gl4 = (const float4*)glds;
  for (int c = 0; c < NCH; ++c) {
    const int b = c & 1;
    // issue next x chunk early (independent)
#pragma unroll
    for (int t = 0; t < 4; ++t) xn[t] = xc[t];
    if (c + 1 < NCH) {
#pragma unroll
      for (int t = 0; t < 4; ++t) xn[t] = xr[t][(c + 1) * 64 + lane];
    }

    // compute chunk c from buf b: 16 ds_read_b128 + 256 FMA per lane
    const float4* gb4 = gl4 + b * (GBUF / 4);
#pragma unroll
    for (int eq = 0; eq < 4; ++eq) {
      const float4 ge0 = gb4[(eq * 4 + 0) * 65 + lane];
      const float4 ge1 = gb4[(eq * 4 + 1) * 65 + lane];
      const float4 ge2 = gb4[(eq * 4 + 2) * 65 + lane];
      const float4 ge3 = gb4[(eq * 4 + 3) * 65 + lane];
#pragma unroll
      for (int t = 0; t < 4; ++t) {
        acc[t][eq*4+0] += xc[t].x*ge0.x + xc[t].y*ge0.y + xc[t].z*ge0.z + xc[t].w*ge0.w;
        acc[t][eq*4+1] += xc[t].x*ge1.x + xc[t].y*ge1.y + xc[t].z*ge1.z + xc[t].w*ge1.w;
        acc[t][eq*4+2] += xc[t].x*ge2.x + xc[t].y*ge2.y + xc[t].z*ge2.z + xc[t].w*ge2.w;
        acc[t][eq*4+3] += xc[t].x*ge3.x + xc[t].y*ge3.y + xc[t].z*ge3.z + xc[t].w*ge3.w;
      }
    }

    // stage gate chunk c+1 into buf b^1; then load regs for chunk c+2
    if (c + 1 < NCH) {
      float* dst = glds + (b ^ 1) * GBUF;
#pragma unroll
      for (int u = 0; u < 4; ++u) {
        int f4 = u * 256 + tid, k = f4 >> 2, j = f4 & 3;
        dst[(4 * j + 0) * GSTR + k] = gr[u].x;
        dst[(4 * j + 1) * GSTR + k] = gr[u].y;
        dst[(4 * j + 2) * GSTR + k] = gr[u].z;
        dst[(4 * j + 3) * GSTR + k] = gr[u].w;
      }
      if (c + 2 < NCH) {
#pragma unroll
        for (int u = 0; u < 4; ++u) gr[u] = gsrc[(c + 2) * 1024 + u * 256 + tid];
      }
    }
#pragma unroll
    for (int t = 0; t < 4; ++t) xc[t] = xn[t];
    __syncthreads();   // buf b readers done + buf b^1 writes visible
  }

  // ---- epilogue: lane-k-partition reduce ----
#pragma unroll
  for (int t = 0; t < 4; ++t)
#pragma unroll
    for (int e = 0; e < NE; ++e) {
      acc[t][e] += __shfl_xor(acc[t][e], 32, 64);
      acc[t][e] += __shfl_xor(acc[t][e], 16, 64);
      acc[t][e] += __shfl_xor(acc[t][e],  8, 64);
    }
  // red[w][grp][t][e] into buf0 region (last compute read buf1; safe)
  if (lane < 8) {
#pragma unroll
    for (int t = 0; t < 4; ++t)
#pragma unroll
      for (int e = 0; e < NE; ++e)
        glds[((w * 8 + lane) * 4 + t) * 16 + e] = acc[t][e];
  }
  __syncthreads();
  {
    int t = tid >> 4, e = tid & 15;                // 256 (token,e) pairs
    int ww = t >> 2, tt = t & 3;
    float s = 0.f;
#pragma unroll
    for (int grp = 0; grp < 8; ++grp)
      s += glds[((ww * 8 + grp) * 4 + tt) * 16 + e];
    ws[((size_t)h * N_TOK + t0 + t) * NE + e] = s; // coalesced 1KB/block
  }
}

// Sum 2 half-partials, top-2 (earliest-index tie-break = jax top_k),
// sigmoid, scatter into (E,N) scores; token_indices[e][t] = t (as float).
__global__ __launch_bounds__(256)
void router_finalize(const float* __restrict__ ws, float* __restrict__ out) {
  int t = blockIdx.x * 256 + threadIdx.x;
  const float4* r0p = (const float4*)(ws + (size_t)t * NE);
  const float4* r1p = (const float4*)(ws + ((size_t)N_TOK + t) * NE);
  float l[NE];
#pragma unroll
  for (int j = 0; j < 4; ++j) {
    float4 a = r0p[j], b = r1p[j];
    l[j*4+0] = a.x + b.x; l[j*4+1] = a.y + b.y;
    l[j*4+2] = a.z + b.z; l[j*4+3] = a.w + b.w;
  }
  int i1 = 0; float v1 = l[0];
#pragma unroll
  for (int e = 1; e < NE; ++e) { if (l[e] > v1) { v1 = l[e]; i1 = e; } }
  int i2 = -1; float v2 = -1e30f;
#pragma unroll
  for (int e = 0; e < NE; ++e) { if (e != i1 && l[e] > v2) { v2 = l[e]; i2 = e; } }
  float s1 = 1.f / (1.f + __expf(-v1));
  float s2 = 1.f / (1.f + __expf(-v2));
  float* scores = out;
  float* tix    = out + (size_t)NE * N_TOK;
  float tf = (float)t;
#pragma unroll
  for (int e = 0; e < NE; ++e) {                   // coalesced across lanes per e
    scores[(size_t)e * N_TOK + t] = (e == i1) ? s1 : ((e == i2) ? s2 : 0.f);
    tix[(size_t)e * N_TOK + t]    = tf;
  }
}

extern "C" void kernel_launch(void* const* d_in, const int* in_sizes, int n_in,
                              void* d_out, int out_size, void* d_ws, size_t ws_size,
                              hipStream_t stream) {
  const float* x    = (const float*)d_in[0];
  const float* gate = (const float*)d_in[1];
  float* out = (float*)d_out;
  float* ws  = (float*)d_ws;   // needs NH*N_TOK*NE*4 = 1 MB
  router_logits<<<dim3(N_TOK / TPB * NH), dim3(256), 0, stream>>>(x, gate, ws);
  router_finalize<<<dim3(N_TOK / 256), dim3(256), 0, stream>>>(ws, out);
}

// Round 11
// 217.544 us; speedup vs baseline: 1.0708x; 1.0708x over previous
//
#include <hip/hip_runtime.h>

#define N_TOK 8192
#define KDIM  4096
#define NE    16
#define TPB   16                   // tokens per block (4 per wave)
#define NH    2                    // K halves (split-K)
#define KH    (KDIM / NH)          // 2048
#define CHUNK 256                  // k per chunk
#define NCH   (KH / CHUNK)         // 8 chunks per half
#define GSTR  260                  // gateT row stride in floats (256 + 4 pad)
#define GBUF  (NE * GSTR)          // 4160 floats per LDS buffer

// R17: R16's 4-token/wave amortization, spill-proofed.
// R16 post-mortem: VGPR_Count=64 (= 512/8: allocator targeted 8 waves/EU)
// but acc[4][16] alone needs 64 -> accumulators spilled to scratch;
// WRITE_SIZE=133MB (vs 5MB ideal) = the smoking gun; logits 97.5us.
// The amortization theory (gate-LDS reads + staging instrs halve per token
// vs R15's 2-token waves) was never actually tested. Fixes:
// (1) amdgpu_waves_per_eu(4,4): pin exactly 4 waves/EU -> 128-VGPR budget,
//     forbids the 8-wave/64-reg target. 16 waves/CU = measured TLP optimum.
// (2) drop xn[4] (-16 regs): rotate xc in place -- next chunk's x loads
//     issue right after the last FMA reading xc, giving staging+barrier
//     distance before next use (same prefetch depth, no extra regs).
//     Demand: acc 64 + xc 16 + gr 16 + addr ~16 = ~112 < 128.
// (3) everything else = R15's proven pipeline (fill-shaped 1KB x reads,
//     transposed gate double-buffer, one barrier/chunk).
// Prediction: VGPR 112-124, WRITE_SIZE -> ~5MB (validity check), logits
// 97.5 -> 45-55us, total -> 175-185. If logits ~60-75 (R15 parity, no
// spill): amortization null -> attack per-chunk stall structure next.
__global__ __attribute__((amdgpu_waves_per_eu(4, 4))) __launch_bounds__(256)
void router_logits(const float* __restrict__ x, const float* __restrict__ gate,
                   float* __restrict__ ws) {
  __shared__ __align__(16) float glds[2 * GBUF];   // 33.3 KB
  const int tid  = threadIdx.x;
  const int lane = tid & 63;
  const int w    = __builtin_amdgcn_readfirstlane(tid >> 6);
  const int g    = blockIdx.x >> 1;                // token group (512)
  const int h    = blockIdx.x & 1;                 // K half
  const int t0   = g * TPB;
  const int tokb = t0 + w * 4;                     // wave's 4 tokens

  const float4* gsrc = (const float4*)gate + (size_t)h * (KH * NE / 4);

  // ---- prologue: stage gate chunk 0 into buf0, load regs for chunk 1 ----
  float4 gr[4];
#pragma unroll
  for (int u = 0; u < 4; ++u) gr[u] = gsrc[u * 256 + tid];
#pragma unroll
  for (int u = 0; u < 4; ++u) {                    // transpose: gateT[e][k]
    int f4 = u * 256 + tid, k = f4 >> 2, j = f4 & 3;
    glds[(4 * j + 0) * GSTR + k] = gr[u].x;
    glds[(4 * j + 1) * GSTR + k] = gr[u].y;
    glds[(4 * j + 2) * GSTR + k] = gr[u].z;
    glds[(4 * j + 3) * GSTR + k] = gr[u].w;
  }
#pragma unroll
  for (int u = 0; u < 4; ++u) gr[u] = gsrc[1024 + u * 256 + tid];

  const float4* xr[4];
#pragma unroll
  for (int t = 0; t < 4; ++t)
    xr[t] = (const float4*)(x + (size_t)(tokb + t) * KDIM) + h * (KH / 4);

  float4 xc[4];
#pragma unroll
  for (int t = 0; t < 4; ++t) xc[t] = xr[t][lane]; // chunk 0: 1KB/instr/wave

  float acc[4][NE];
#pragma unroll
  for (int t = 0; t < 4; ++t)
#pragma unroll
    for (int e = 0; e < NE; ++e) acc[t][e] = 0.f;

  __syncthreads();                                 // buf0 visible

  const float4* gl4 = (const float4*)glds;
  for (int c = 0; c < NCH; ++c) {
    const int b = c & 1;

    // compute chunk c from buf b: 16 ds_read_b128 + 256 FMA per lane
    const float4* gb4 = gl4 + b * (GBUF / 4);
#pragma unroll
    for (int eq = 0; eq < 4; ++eq) {
      const float4 ge0 = gb4[(eq * 4 + 0) * 65 + lane];
      const float4 ge1 = gb4[(eq * 4 + 1) * 65 + lane];
      const float4 ge2 = gb4[(eq * 4 + 2) * 65 + lane];
      const float4 ge3 = gb4[(eq * 4 + 3) * 65 + lane];
#pragma unroll
      for (int t = 0; t < 4; ++t) {
        acc[t][eq*4+0] += xc[t].x*ge0.x + xc[t].y*ge0.y + xc[t].z*ge0.z + xc[t].w*ge0.w;
        acc[t][eq*4+1] += xc[t].x*ge1.x + xc[t].y*ge1.y + xc[t].z*ge1.z + xc[t].w*ge1.w;
        acc[t][eq*4+2] += xc[t].x*ge2.x + xc[t].y*ge2.y + xc[t].z*ge2.z + xc[t].w*ge2.w;
        acc[t][eq*4+3] += xc[t].x*ge3.x + xc[t].y*ge3.y + xc[t].z*ge3.z + xc[t].w*ge3.w;
      }
    }

    // rotate xc in place: issue next chunk's x loads right after last use
    if (c + 1 < NCH) {
#pragma unroll
      for (int t = 0; t < 4; ++t) xc[t] = xr[t][(c + 1) * 64 + lane];
    }

    // stage gate chunk c+1 into buf b^1; then load regs for chunk c+2
    if (c + 1 < NCH) {
      float* dst = glds + (b ^ 1) * GBUF;
#pragma unroll
      for (int u = 0; u < 4; ++u) {
        int f4 = u * 256 + tid, k = f4 >> 2, j = f4 & 3;
        dst[(4 * j + 0) * GSTR + k] = gr[u].x;
        dst[(4 * j + 1) * GSTR + k] = gr[u].y;
        dst[(4 * j + 2) * GSTR + k] = gr[u].z;
        dst[(4 * j + 3) * GSTR + k] = gr[u].w;
      }
      if (c + 2 < NCH) {
#pragma unroll
        for (int u = 0; u < 4; ++u) gr[u] = gsrc[(c + 2) * 1024 + u * 256 + tid];
      }
    }
    __syncthreads();   // buf b readers done + buf b^1 writes visible
  }

  // ---- epilogue: lane-k-partition reduce ----
#pragma unroll
  for (int t = 0; t < 4; ++t)
#pragma unroll
    for (int e = 0; e < NE; ++e) {
      acc[t][e] += __shfl_xor(acc[t][e], 32, 64);
      acc[t][e] += __shfl_xor(acc[t][e], 16, 64);
      acc[t][e] += __shfl_xor(acc[t][e],  8, 64);
    }
  // red[w][grp][t][e] into buf0 region (last compute read buf1; safe)
  if (lane < 8) {
#pragma unroll
    for (int t = 0; t < 4; ++t)
#pragma unroll
      for (int e = 0; e < NE; ++e)
        glds[((w * 8 + lane) * 4 + t) * 16 + e] = acc[t][e];
  }
  __syncthreads();
  {
    int t = tid >> 4, e = tid & 15;                // 256 (token,e) pairs
    int ww = t >> 2, tt = t & 3;
    float s = 0.f;
#pragma unroll
    for (int grp = 0; grp < 8; ++grp)
      s += glds[((ww * 8 + grp) * 4 + tt) * 16 + e];
    ws[((size_t)h * N_TOK + t0 + t) * NE + e] = s; // coalesced 1KB/block
  }
}

// Sum 2 half-partials, top-2 (earliest-index tie-break = jax top_k),
// sigmoid, scatter into (E,N) scores; token_indices[e][t] = t (as float).
__global__ __launch_bounds__(256)
void router_finalize(const float* __restrict__ ws, float* __restrict__ out) {
  int t = blockIdx.x * 256 + threadIdx.x;
  const float4* r0p = (const float4*)(ws + (size_t)t * NE);
  const float4* r1p = (const float4*)(ws + ((size_t)N_TOK + t) * NE);
  float l[NE];
#pragma unroll
  for (int j = 0; j < 4; ++j) {
    float4 a = r0p[j], b = r1p[j];
    l[j*4+0] = a.x + b.x; l[j*4+1] = a.y + b.y;
    l[j*4+2] = a.z + b.z; l[j*4+3] = a.w + b.w;
  }
  int i1 = 0; float v1 = l[0];
#pragma unroll
  for (int e = 1; e < NE; ++e) { if (l[e] > v1) { v1 = l[e]; i1 = e; } }
  int i2 = -1; float v2 = -1e30f;
#pragma unroll
  for (int e = 0; e < NE; ++e) { if (e != i1 && l[e] > v2) { v2 = l[e]; i2 = e; } }
  float s1 = 1.f / (1.f + __expf(-v1));
  float s2 = 1.f / (1.f + __expf(-v2));
  float* scores = out;
  float* tix    = out + (size_t)NE * N_TOK;
  float tf = (float)t;
#pragma unroll
  for (int e = 0; e < NE; ++e) {                   // coalesced across lanes per e
    scores[(size_t)e * N_TOK + t] = (e == i1) ? s1 : ((e == i2) ? s2 : 0.f);
    tix[(size_t)e * N_TOK + t]    = tf;
  }
}

extern "C" void kernel_launch(void* const* d_in, const int* in_sizes, int n_in,
                              void* d_out, int out_size, void* d_ws, size_t ws_size,
                              hipStream_t stream) {
  const float* x    = (const float*)d_in[0];
  const float* gate = (const float*)d_in[1];
  float* out = (float*)d_out;
  float* ws  = (float*)d_ws;   // needs NH*N_TOK*NE*4 = 1 MB
  router_logits<<<dim3(N_TOK / TPB * NH), dim3(256), 0, stream>>>(x, gate, ws);
  router_finalize<<<dim3(N_TOK / 256), dim3(256), 0, stream>>>(ws, out);
}